// Round 1
// baseline (411.885 us; speedup 1.0000x reference)
//
#include <hip/hip_runtime.h>

// GCN 2-layer forward, f32.
// x[N,64], edge_index[2,E] (int32 on device), W1[64,64], b1[64], W2[64,16], b2[16]
// out[N,16] = log_softmax( agg2 + b2 ), agg = D^-1/2 A D^-1/2 (with self loops)

#define F1 64
#define F2 16

__global__ void k_deg_init(float* __restrict__ deg, int n) {
    int i = blockIdx.x * blockDim.x + threadIdx.x;
    if (i < n) deg[i] = 1.0f;  // self-loop contributes 1
}

__global__ void k_deg_edges(const int* __restrict__ dst, float* __restrict__ deg, int e) {
    int i = blockIdx.x * blockDim.x + threadIdx.x;
    if (i < e) atomicAdd(&deg[dst[i]], 1.0f);
}

__global__ void k_dinv(float* __restrict__ deg, int n) {
    int i = blockIdx.x * blockDim.x + threadIdx.x;
    if (i < n) deg[i] = rsqrtf(deg[i]);  // deg >= 1 always (self loop)
}

// h = x @ W1 ; one wave per row, 4 rows/block. W1 staged in LDS.
__global__ __launch_bounds__(256) void k_gemm1(const float* __restrict__ x,
                                               const float* __restrict__ W1,
                                               float* __restrict__ h, int n) {
    __shared__ float w[F1 * F1];
    int tid = threadIdx.x;
    for (int i = tid; i < F1 * F1; i += 256) w[i] = W1[i];
    __syncthreads();
    int wave = tid >> 6, lane = tid & 63;
    int row = blockIdx.x * 4 + wave;
    if (row >= n) return;
    float xv = x[row * F1 + lane];
    float s = 0.0f;
#pragma unroll
    for (int k = 0; k < F1; ++k) {
        float xk = __shfl(xv, k, 64);
        s = fmaf(xk, w[k * F1 + lane], s);  // lane j -> column j; 2-way bank alias (free)
    }
    h[row * F1 + lane] = s;
}

// agg[i][:] = dinv[i]^2 * h[i][:]   (self-loop term; also initializes agg buffer)
__global__ void k_self(const float* __restrict__ h, const float* __restrict__ dinv,
                       float* __restrict__ agg, int total, int shift) {
    int idx = blockIdx.x * blockDim.x + threadIdx.x;
    if (idx < total) {
        float di = dinv[idx >> shift];
        agg[idx] = di * di * h[idx];
    }
}

// per-edge scatter, f=64: one wave per edge, lane = feature
__global__ __launch_bounds__(256) void k_edge64(const int* __restrict__ src, const int* __restrict__ dst,
                                                const float* __restrict__ dinv,
                                                const float* __restrict__ h,
                                                float* __restrict__ agg, int e) {
    int idx = blockIdx.x * blockDim.x + threadIdx.x;
    int ed = idx >> 6, j = idx & 63;
    if (ed >= e) return;
    int s = src[ed], d = dst[ed];
    float w = dinv[s] * dinv[d];
    atomicAdd(&agg[d * F1 + j], w * h[s * F1 + j]);
}

// per-edge scatter, f=16
__global__ __launch_bounds__(256) void k_edge16(const int* __restrict__ src, const int* __restrict__ dst,
                                                const float* __restrict__ dinv,
                                                const float* __restrict__ h2,
                                                float* __restrict__ agg, int e) {
    int idx = blockIdx.x * blockDim.x + threadIdx.x;
    int ed = idx >> 4, j = idx & 15;
    if (ed >= e) return;
    int s = src[ed], d = dst[ed];
    float w = dinv[s] * dinv[d];
    atomicAdd(&agg[d * F2 + j], w * h2[s * F2 + j]);
}

// h2 = relu(agg1 + b1) @ W2 ; one thread per output element (row,j)
__global__ __launch_bounds__(256) void k_gemm2(const float* __restrict__ agg1,
                                               const float* __restrict__ b1,
                                               const float* __restrict__ W2,
                                               float* __restrict__ h2, int n) {
    __shared__ float w[F1 * F2];
    __shared__ float bb[F1];
    int tid = threadIdx.x;
    for (int i = tid; i < F1 * F2; i += 256) w[i] = W2[i];
    if (tid < F1) bb[tid] = b1[tid];
    __syncthreads();
    int idx = blockIdx.x * 256 + tid;
    int row = idx >> 4, j = idx & 15;
    if (row >= n) return;
    float s = 0.0f;
#pragma unroll
    for (int k = 0; k < F1; ++k) {
        float a = fmaxf(agg1[row * F1 + k] + bb[k], 0.0f);
        s = fmaf(a, w[k * F2 + j], s);
    }
    h2[row * F2 + j] = s;
}

// in-place: out[row][:16] = log_softmax(out[row][:16] + b2)
__global__ void k_lsm(float* __restrict__ out, const float* __restrict__ b2, int n) {
    int row = blockIdx.x * blockDim.x + threadIdx.x;
    if (row >= n) return;
    float v[F2];
    float m = -1e30f;
#pragma unroll
    for (int j = 0; j < F2; ++j) {
        v[j] = out[row * F2 + j] + b2[j];
        m = fmaxf(m, v[j]);
    }
    float sum = 0.0f;
#pragma unroll
    for (int j = 0; j < F2; ++j) sum += expf(v[j] - m);
    float l = m + logf(sum);
#pragma unroll
    for (int j = 0; j < F2; ++j) out[row * F2 + j] = v[j] - l;
}

extern "C" void kernel_launch(void* const* d_in, const int* in_sizes, int n_in,
                              void* d_out, int out_size, void* d_ws, size_t ws_size,
                              hipStream_t stream) {
    const float* x  = (const float*)d_in[0];
    const int*   ei = (const int*)d_in[1];
    const float* W1 = (const float*)d_in[2];
    const float* b1 = (const float*)d_in[3];
    const float* W2 = (const float*)d_in[4];
    const float* b2 = (const float*)d_in[5];
    float* out = (float*)d_out;

    const int n = in_sizes[0] / F1;       // 50000
    const int e = in_sizes[1] / 2;        // 800000
    const int* src = ei;
    const int* dst = ei + e;

    // workspace layout (floats): dinv[n] | h[n*64] | agg1[n*64]; h reused as h2
    float* dinv = (float*)d_ws;
    float* h    = dinv + ((n + 63) & ~63);
    float* agg1 = h + n * F1;

    const int B = 256;
    // degrees -> dinv
    k_deg_init<<<(n + B - 1) / B, B, 0, stream>>>(dinv, n);
    k_deg_edges<<<(e + B - 1) / B, B, 0, stream>>>(dst, dinv, e);
    k_dinv<<<(n + B - 1) / B, B, 0, stream>>>(dinv, n);

    // layer 1
    k_gemm1<<<(n + 3) / 4, B, 0, stream>>>(x, W1, h, n);
    k_self<<<(n * F1 + B - 1) / B, B, 0, stream>>>(h, dinv, agg1, n * F1, 6);
    k_edge64<<<(e * F1 + B - 1) / B, B, 0, stream>>>(src, dst, dinv, h, agg1, e);

    // layer 2 (bias1+relu fused into gemm2 load); h2 reuses h buffer
    float* h2 = h;
    k_gemm2<<<(n * F2 + B - 1) / B, B, 0, stream>>>(agg1, b1, W2, h2, n);
    k_self<<<(n * F2 + B - 1) / B, B, 0, stream>>>(h2, dinv, out, n * F2, 4);
    k_edge16<<<(e * F2 + B - 1) / B, B, 0, stream>>>(src, dst, dinv, h2, out, e);

    // bias2 + log_softmax in-place
    k_lsm<<<(n + B - 1) / B, B, 0, stream>>>(out, b2, n);
}

// Round 2
// 301.953 us; speedup vs baseline: 1.3641x; 1.3641x over previous
//
#include <hip/hip_runtime.h>

// GCN 2-layer forward, f32, CSR gather-based aggregation (no f32 atomics).
// x[N,64], edge_index[2,E], W1[64,64], b1[64], W2[64,16], b2[16]
// out[N,16] = log_softmax(agg2 + b2), agg = D^-1/2 (A+I) D^-1/2 on h=XW

#define F1 64
#define F2 16

__global__ void k_zero_int(int* __restrict__ p, int n) {
    int i = blockIdx.x * blockDim.x + threadIdx.x;
    if (i < n) p[i] = 0;
}

__global__ void k_count(const int* __restrict__ dst, int* __restrict__ cnt, int e) {
    int i = blockIdx.x * blockDim.x + threadIdx.x;
    if (i < e) atomicAdd(&cnt[dst[i]], 1);
}

__global__ void k_dinv(const int* __restrict__ cnt, float* __restrict__ dinv, int n) {
    int i = blockIdx.x * blockDim.x + threadIdx.x;
    if (i < n) dinv[i] = rsqrtf((float)cnt[i] + 1.0f);  // +1 self loop
}

// block-local exclusive scan of cnt -> rowstart, block totals -> bsum
__global__ __launch_bounds__(256) void k_scan1(const int* __restrict__ cnt,
                                               int* __restrict__ rowstart,
                                               int* __restrict__ bsum, int n) {
    __shared__ int s[256];
    int tid = threadIdx.x, i = blockIdx.x * 256 + tid;
    int v = (i < n) ? cnt[i] : 0;
    s[tid] = v;
    __syncthreads();
    for (int off = 1; off < 256; off <<= 1) {
        int t = (tid >= off) ? s[tid - off] : 0;
        __syncthreads();
        s[tid] += t;
        __syncthreads();
    }
    if (i < n) rowstart[i] = s[tid] - v;  // exclusive
    if (tid == 255) bsum[blockIdx.x] = s[255];
}

// single-block exclusive scan of block sums (nb <= 256)
__global__ __launch_bounds__(256) void k_scan2(int* __restrict__ bsum, int nb) {
    __shared__ int s[256];
    int tid = threadIdx.x;
    int v = (tid < nb) ? bsum[tid] : 0;
    s[tid] = v;
    __syncthreads();
    for (int off = 1; off < 256; off <<= 1) {
        int t = (tid >= off) ? s[tid - off] : 0;
        __syncthreads();
        s[tid] += t;
        __syncthreads();
    }
    if (tid < nb) bsum[tid] = s[tid] - v;  // exclusive
}

__global__ __launch_bounds__(256) void k_scan3(int* __restrict__ rowstart,
                                               int* __restrict__ cursor,
                                               const int* __restrict__ bsum, int n, int e) {
    int i = blockIdx.x * 256 + threadIdx.x;
    if (i < n) {
        int r = rowstart[i] + bsum[blockIdx.x];
        rowstart[i] = r;
        cursor[i] = r;
    }
    if (i == 0) rowstart[n] = e;
}

__global__ void k_fill(const int* __restrict__ src, const int* __restrict__ dst,
                       int* __restrict__ cursor, int* __restrict__ csr, int e) {
    int i = blockIdx.x * blockDim.x + threadIdx.x;
    if (i < e) {
        int pos = atomicAdd(&cursor[dst[i]], 1);
        csr[pos] = src[i];
    }
}

// h = x @ W1 ; one wave per row, 4 rows/block, W1 in LDS.
__global__ __launch_bounds__(256) void k_gemm1(const float* __restrict__ x,
                                               const float* __restrict__ W1,
                                               float* __restrict__ h, int n) {
    __shared__ float w[F1 * F1];
    int tid = threadIdx.x;
    for (int i = tid; i < F1 * F1; i += 256) w[i] = W1[i];
    __syncthreads();
    int wave = tid >> 6, lane = tid & 63;
    int row = blockIdx.x * 4 + wave;
    if (row >= n) return;
    float xv = x[row * F1 + lane];
    float s = 0.0f;
#pragma unroll
    for (int k = 0; k < F1; ++k) {
        float xk = __shfl(xv, k, 64);
        s = fmaf(xk, w[k * F1 + lane], s);
    }
    h[row * F1 + lane] = s;
}

// gather-aggregate layer 1: one wave per node, lane = feature (64)
__global__ __launch_bounds__(256) void k_agg64(const int* __restrict__ rowstart,
                                               const int* __restrict__ csr,
                                               const float* __restrict__ dinv,
                                               const float* __restrict__ h,
                                               float* __restrict__ agg, int n) {
    int wave = threadIdx.x >> 6, lane = threadIdx.x & 63;
    int node = blockIdx.x * 4 + wave;
    if (node >= n) return;
    float di = dinv[node];
    float acc = di * di * h[node * F1 + lane];  // self-loop term
    int beg = rowstart[node], end = rowstart[node + 1];
    for (int base = beg; base < end; base += 64) {
        int m = end - base; m = m > 64 ? 64 : m;
        int k = base + lane;
        int idx = (k < end) ? csr[k] : 0;          // coalesced batch of src ids
        float dv = (k < end) ? dinv[idx] : 0.0f;   // batched dinv gather
        for (int kk = 0; kk < m; ++kk) {
            int s = __shfl(idx, kk, 64);
            float w = __shfl(dv, kk, 64) * di;
            acc = fmaf(w, h[s * F1 + lane], acc);  // coalesced 256B row gather
        }
    }
    agg[node * F1 + lane] = acc;
}

// h2 = relu(agg1 + b1) @ W2 ; one thread per (row, j)
__global__ __launch_bounds__(256) void k_gemm2(const float* __restrict__ agg1,
                                               const float* __restrict__ b1,
                                               const float* __restrict__ W2,
                                               float* __restrict__ h2, int n) {
    __shared__ float w[F1 * F2];
    __shared__ float bb[F1];
    int tid = threadIdx.x;
    for (int i = tid; i < F1 * F2; i += 256) w[i] = W2[i];
    if (tid < F1) bb[tid] = b1[tid];
    __syncthreads();
    int idx = blockIdx.x * 256 + tid;
    int row = idx >> 4, j = idx & 15;
    if (row >= n) return;
    float s = 0.0f;
#pragma unroll
    for (int k = 0; k < F1; ++k) {
        float a = fmaxf(agg1[row * F1 + k] + bb[k], 0.0f);
        s = fmaf(a, w[k * F2 + j], s);
    }
    h2[row * F2 + j] = s;
}

// gather-aggregate layer 2 (16 feats) + b2 + log-softmax fused.
// 16 lanes per node, 16 nodes per 256-block.
__global__ __launch_bounds__(256) void k_agg16_lsm(const int* __restrict__ rowstart,
                                                   const int* __restrict__ csr,
                                                   const float* __restrict__ dinv,
                                                   const float* __restrict__ h2,
                                                   const float* __restrict__ b2,
                                                   float* __restrict__ out, int n) {
    int tid = threadIdx.x;
    int grp = tid >> 4, lane = tid & 15;
    int node = blockIdx.x * 16 + grp;
    if (node >= n) return;
    float di = dinv[node];
    float acc = di * di * h2[node * F2 + lane];
    int beg = rowstart[node], end = rowstart[node + 1];
    for (int base = beg; base < end; base += 16) {
        int m = end - base; m = m > 16 ? 16 : m;
        int k = base + lane;
        int idx = (k < end) ? csr[k] : 0;
        float dv = (k < end) ? dinv[idx] : 0.0f;
        for (int kk = 0; kk < m; ++kk) {
            int s = __shfl(idx, kk, 16);
            float w = __shfl(dv, kk, 16) * di;
            acc = fmaf(w, h2[s * F2 + lane], acc);
        }
    }
    // fused bias + log-softmax across the 16-lane group
    float v = acc + b2[lane];
    float mx = v;
    for (int o = 1; o < 16; o <<= 1) mx = fmaxf(mx, __shfl_xor(mx, o, 16));
    float ex = expf(v - mx);
    float sm = ex;
    for (int o = 1; o < 16; o <<= 1) sm += __shfl_xor(sm, o, 16);
    out[node * F2 + lane] = v - mx - logf(sm);
}

extern "C" void kernel_launch(void* const* d_in, const int* in_sizes, int n_in,
                              void* d_out, int out_size, void* d_ws, size_t ws_size,
                              hipStream_t stream) {
    const float* x  = (const float*)d_in[0];
    const int*   ei = (const int*)d_in[1];
    const float* W1 = (const float*)d_in[2];
    const float* b1 = (const float*)d_in[3];
    const float* W2 = (const float*)d_in[4];
    const float* b2 = (const float*)d_in[5];
    float* out = (float*)d_out;

    const int n = in_sizes[0] / F1;   // 50000
    const int e = in_sizes[1] / 2;    // 800000
    const int* src = ei;
    const int* dst = ei + e;

    const int na = (n + 63) & ~63;
    const int nb = (n + 255) / 256;   // scan blocks (196 <= 256)

    // ws layout (4-byte units):
    // dinv[na] | cnt/cursor[na] | rowstart[na+64] | bsum[256] | csr[e] | h[n*64] | agg1[n*64]
    float* dinv   = (float*)d_ws;
    int* cnt      = (int*)(dinv + na);       // reused as cursor after scan
    int* rowstart = cnt + na;
    int* bsum     = rowstart + na + 64;
    int* csr      = bsum + 256;
    float* h      = (float*)(csr + ((e + 63) & ~63));
    float* agg1   = h + (size_t)n * F1;

    const int B = 256;
    // ---- CSR build + dinv ----
    k_zero_int<<<(n + B - 1) / B, B, 0, stream>>>(cnt, n);
    k_count<<<(e + B - 1) / B, B, 0, stream>>>(dst, cnt, e);
    k_dinv<<<(n + B - 1) / B, B, 0, stream>>>(cnt, dinv, n);
    k_scan1<<<nb, B, 0, stream>>>(cnt, rowstart, bsum, n);
    k_scan2<<<1, B, 0, stream>>>(bsum, nb);
    k_scan3<<<nb, B, 0, stream>>>(rowstart, cnt /*cursor*/, bsum, n, e);
    k_fill<<<(e + B - 1) / B, B, 0, stream>>>(src, dst, cnt /*cursor*/, csr, e);

    // ---- layer 1 ----
    k_gemm1<<<(n + 3) / 4, B, 0, stream>>>(x, W1, h, n);
    k_agg64<<<(n + 3) / 4, B, 0, stream>>>(rowstart, csr, dinv, h, agg1, n);

    // ---- layer 2 (bias1+relu fused in gemm2; bias2+log-softmax fused in agg) ----
    float* h2 = h;  // reuse
    k_gemm2<<<(n * F2 + B - 1) / B, B, 0, stream>>>(agg1, b1, W2, h2, n);
    k_agg16_lsm<<<(n + 15) / 16, B, 0, stream>>>(rowstart, csr, dinv, h2, b2, out, n);
}

// Round 3
// 231.148 us; speedup vs baseline: 1.7819x; 1.3063x over previous
//
#include <hip/hip_runtime.h>

// GCN 2-layer forward. CSR gather aggregation (no f32 atomics),
// GEMMs via 3-term bf16-split MFMA (f32-grade accuracy).

#define F1 64
#define F2 16

typedef __attribute__((ext_vector_type(8))) short bf16x8;
typedef __attribute__((ext_vector_type(4))) float f32x4;

// split 8 f32 into hi/lo bf16 fragments (truncation split: hi exact, |lo err| ~2^-17 rel)
__device__ inline void cvt8(const float* v, bf16x8& h, bf16x8& l) {
#pragma unroll
    for (int i = 0; i < 8; ++i) {
        unsigned b = __float_as_uint(v[i]);
        h[i] = (short)(b >> 16);
        float hif = __uint_as_float(b & 0xFFFF0000u);
        float lof = v[i] - hif;
        l[i] = (short)(__float_as_uint(lof) >> 16);
    }
}

__global__ void k_count(const int* __restrict__ dst, int* __restrict__ cnt, int e4) {
    int i = blockIdx.x * blockDim.x + threadIdx.x;
    if (i < e4) {
        int4 d = ((const int4*)dst)[i];
        atomicAdd(&cnt[d.x], 1);
        atomicAdd(&cnt[d.y], 1);
        atomicAdd(&cnt[d.z], 1);
        atomicAdd(&cnt[d.w], 1);
    }
}

// block-local exclusive scan of cnt -> rowstart, block totals -> bsum; dinv fused
__global__ __launch_bounds__(256) void k_scan1(const int* __restrict__ cnt,
                                               int* __restrict__ rowstart,
                                               int* __restrict__ bsum,
                                               float* __restrict__ dinv, int n) {
    __shared__ int s[256];
    int tid = threadIdx.x, i = blockIdx.x * 256 + tid;
    int v = (i < n) ? cnt[i] : 0;
    if (i < n) dinv[i] = rsqrtf((float)v + 1.0f);  // +1 self loop
    s[tid] = v;
    __syncthreads();
    for (int off = 1; off < 256; off <<= 1) {
        int t = (tid >= off) ? s[tid - off] : 0;
        __syncthreads();
        s[tid] += t;
        __syncthreads();
    }
    if (i < n) rowstart[i] = s[tid] - v;  // exclusive
    if (tid == 255) bsum[blockIdx.x] = s[255];
}

__global__ __launch_bounds__(256) void k_scan2(int* __restrict__ bsum, int nb) {
    __shared__ int s[256];
    int tid = threadIdx.x;
    int v = (tid < nb) ? bsum[tid] : 0;
    s[tid] = v;
    __syncthreads();
    for (int off = 1; off < 256; off <<= 1) {
        int t = (tid >= off) ? s[tid - off] : 0;
        __syncthreads();
        s[tid] += t;
        __syncthreads();
    }
    if (tid < nb) bsum[tid] = s[tid] - v;
}

__global__ __launch_bounds__(256) void k_scan3(int* __restrict__ rowstart,
                                               int* __restrict__ cursor,
                                               const int* __restrict__ bsum, int n, int e) {
    int i = blockIdx.x * 256 + threadIdx.x;
    if (i < n) {
        int r = rowstart[i] + bsum[blockIdx.x];
        rowstart[i] = r;
        cursor[i] = r;
    }
    if (i == 0) rowstart[n] = e;
}

__global__ void k_fill(const int* __restrict__ src, const int* __restrict__ dst,
                       int* __restrict__ cursor, int* __restrict__ csr, int e4) {
    int i = blockIdx.x * blockDim.x + threadIdx.x;
    if (i < e4) {
        int4 s4 = ((const int4*)src)[i];
        int4 d4 = ((const int4*)dst)[i];
        int p;
        p = atomicAdd(&cursor[d4.x], 1); csr[p] = s4.x;
        p = atomicAdd(&cursor[d4.y], 1); csr[p] = s4.y;
        p = atomicAdd(&cursor[d4.z], 1); csr[p] = s4.z;
        p = atomicAdd(&cursor[d4.w], 1); csr[p] = s4.w;
    }
}

// h = x @ W1 via MFMA. Block: 4 waves x 16 rows = 64 rows, all 64 cols.
__global__ __launch_bounds__(256) void k_mgemm1(const float* __restrict__ x,
                                                const float* __restrict__ W1,
                                                float* __restrict__ h, int n) {
    __shared__ float ws[64 * 65];  // stride 65: conflict-free strided frag reads
    int tid = threadIdx.x;
    for (int i = tid; i < 64 * 64; i += 256) {
        int k = i >> 6, c = i & 63;
        ws[k * 65 + c] = W1[i];
    }
    __syncthreads();
    int lane = tid & 63, wv = tid >> 6;
    int rt = blockIdx.x * 64 + wv * 16;
    int r = lane & 15, g = lane >> 4;
    int row = rt + r;
    int rowc = row < n ? row : n - 1;
    const float* xp = x + (size_t)rowc * F1 + g * 8;
    bf16x8 ah[2], al[2];
#pragma unroll
    for (int kb = 0; kb < 2; ++kb) {
        float v[8];
        *(float4*)&v[0] = *(const float4*)(xp + kb * 32);
        *(float4*)&v[4] = *(const float4*)(xp + kb * 32 + 4);
        cvt8(v, ah[kb], al[kb]);
    }
#pragma unroll
    for (int ct = 0; ct < 4; ++ct) {
        bf16x8 bh[2], bl[2];
#pragma unroll
        for (int kb = 0; kb < 2; ++kb) {
            float v[8];
#pragma unroll
            for (int i = 0; i < 8; ++i)
                v[i] = ws[(kb * 32 + g * 8 + i) * 65 + ct * 16 + r];
            cvt8(v, bh[kb], bl[kb]);
        }
        f32x4 acc = {0.f, 0.f, 0.f, 0.f};
#pragma unroll
        for (int kb = 0; kb < 2; ++kb) {
            acc = __builtin_amdgcn_mfma_f32_16x16x32_bf16(ah[kb], bh[kb], acc, 0, 0, 0);
            acc = __builtin_amdgcn_mfma_f32_16x16x32_bf16(al[kb], bh[kb], acc, 0, 0, 0);
            acc = __builtin_amdgcn_mfma_f32_16x16x32_bf16(ah[kb], bl[kb], acc, 0, 0, 0);
        }
#pragma unroll
        for (int j = 0; j < 4; ++j) {
            int orow = rt + g * 4 + j;
            if (orow < n) h[(size_t)orow * F1 + ct * 16 + r] = acc[j];
        }
    }
}

// h2 = relu(agg1 + b1) @ W2 via MFMA (16 cols).
__global__ __launch_bounds__(256) void k_mgemm2(const float* __restrict__ agg1,
                                                const float* __restrict__ b1,
                                                const float* __restrict__ W2,
                                                float* __restrict__ h2, int n) {
    __shared__ float ws[64 * 17];
    int tid = threadIdx.x;
    for (int i = tid; i < 64 * 16; i += 256) {
        int k = i >> 4, c = i & 15;
        ws[k * 17 + c] = W2[i];
    }
    __syncthreads();
    int lane = tid & 63, wv = tid >> 6;
    int rt = blockIdx.x * 64 + wv * 16;
    int r = lane & 15, g = lane >> 4;
    int row = rt + r;
    int rowc = row < n ? row : n - 1;
    const float* ap = agg1 + (size_t)rowc * F1 + g * 8;
    const float* bp = b1 + g * 8;
    bf16x8 ah[2], al[2];
#pragma unroll
    for (int kb = 0; kb < 2; ++kb) {
        float v[8], b[8];
        *(float4*)&v[0] = *(const float4*)(ap + kb * 32);
        *(float4*)&v[4] = *(const float4*)(ap + kb * 32 + 4);
        *(float4*)&b[0] = *(const float4*)(bp + kb * 32);
        *(float4*)&b[4] = *(const float4*)(bp + kb * 32 + 4);
#pragma unroll
        for (int i = 0; i < 8; ++i) v[i] = fmaxf(v[i] + b[i], 0.f);
        cvt8(v, ah[kb], al[kb]);
    }
    bf16x8 bh[2], bl[2];
#pragma unroll
    for (int kb = 0; kb < 2; ++kb) {
        float v[8];
#pragma unroll
        for (int i = 0; i < 8; ++i)
            v[i] = ws[(kb * 32 + g * 8 + i) * 17 + r];
        cvt8(v, bh[kb], bl[kb]);
    }
    f32x4 acc = {0.f, 0.f, 0.f, 0.f};
#pragma unroll
    for (int kb = 0; kb < 2; ++kb) {
        acc = __builtin_amdgcn_mfma_f32_16x16x32_bf16(ah[kb], bh[kb], acc, 0, 0, 0);
        acc = __builtin_amdgcn_mfma_f32_16x16x32_bf16(al[kb], bh[kb], acc, 0, 0, 0);
        acc = __builtin_amdgcn_mfma_f32_16x16x32_bf16(ah[kb], bl[kb], acc, 0, 0, 0);
    }
#pragma unroll
    for (int j = 0; j < 4; ++j) {
        int orow = rt + g * 4 + j;
        if (orow < n) h2[(size_t)orow * F2 + r] = acc[j];
    }
}

// layer-1 aggregation: wave per node; lanes = 4 edge-slots x 16 feature-quads (float4)
__global__ __launch_bounds__(256) void k_agg64(const int* __restrict__ rowstart,
                                               const int* __restrict__ csr,
                                               const float* __restrict__ dinv,
                                               const float* __restrict__ h,
                                               float* __restrict__ agg, int n) {
    int lane = threadIdx.x & 63, wv = threadIdx.x >> 6;
    int node = blockIdx.x * 4 + wv;
    if (node >= n) return;
    int g = lane >> 4, q = lane & 15;
    float di = dinv[node];
    const float4* h4 = (const float4*)h;
    float4 acc = {0.f, 0.f, 0.f, 0.f};
    int beg = rowstart[node], end = rowstart[node + 1];
    for (int base = beg; base < end; base += 64) {
        int k = base + lane;
        int idx = (k < end) ? csr[k] : 0;
        float dv = (k < end) ? dinv[idx] : 0.0f;
        int m = end - base;
        if (m > 64) m = 64;
        int iters = (m + 3) >> 2;
        for (int i = 0; i < iters; ++i) {
            int slot = i * 4 + g;
            int s = __shfl(idx, slot, 64);
            float w = __shfl(dv, slot, 64);
            float4 v = h4[(size_t)s * 16 + q];
            acc.x = fmaf(w, v.x, acc.x);
            acc.y = fmaf(w, v.y, acc.y);
            acc.z = fmaf(w, v.z, acc.z);
            acc.w = fmaf(w, v.w, acc.w);
        }
    }
#pragma unroll
    for (int off = 16; off <= 32; off <<= 1) {
        acc.x += __shfl_xor(acc.x, off, 64);
        acc.y += __shfl_xor(acc.y, off, 64);
        acc.z += __shfl_xor(acc.z, off, 64);
        acc.w += __shfl_xor(acc.w, off, 64);
    }
    if (g == 0) {
        float4 sv = h4[(size_t)node * 16 + q];
        float d2 = di * di;
        float4 o;
        o.x = fmaf(di, acc.x, d2 * sv.x);
        o.y = fmaf(di, acc.y, d2 * sv.y);
        o.z = fmaf(di, acc.z, d2 * sv.z);
        o.w = fmaf(di, acc.w, d2 * sv.w);
        ((float4*)agg)[(size_t)node * 16 + q] = o;
    }
}

// layer-2 aggregation + bias + log-softmax: lanes = 16 edge-slots x 4 quads
__global__ __launch_bounds__(256) void k_agg16(const int* __restrict__ rowstart,
                                               const int* __restrict__ csr,
                                               const float* __restrict__ dinv,
                                               const float* __restrict__ h2,
                                               const float* __restrict__ b2,
                                               float* __restrict__ out, int n) {
    int lane = threadIdx.x & 63, wv = threadIdx.x >> 6;
    int node = blockIdx.x * 4 + wv;
    if (node >= n) return;
    int g = lane >> 2, q = lane & 3;
    float di = dinv[node];
    const float4* h4 = (const float4*)h2;
    float4 acc = {0.f, 0.f, 0.f, 0.f};
    int beg = rowstart[node], end = rowstart[node + 1];
    for (int base = beg; base < end; base += 64) {
        int k = base + lane;
        int idx = (k < end) ? csr[k] : 0;
        float dv = (k < end) ? dinv[idx] : 0.0f;
        int m = end - base;
        if (m > 64) m = 64;
        int iters = (m + 15) >> 4;
        for (int i = 0; i < iters; ++i) {
            int slot = i * 16 + g;
            int s = __shfl(idx, slot, 64);
            float w = __shfl(dv, slot, 64);
            float4 v = h4[(size_t)s * 4 + q];
            acc.x = fmaf(w, v.x, acc.x);
            acc.y = fmaf(w, v.y, acc.y);
            acc.z = fmaf(w, v.z, acc.z);
            acc.w = fmaf(w, v.w, acc.w);
        }
    }
#pragma unroll
    for (int off = 4; off <= 32; off <<= 1) {
        acc.x += __shfl_xor(acc.x, off, 64);
        acc.y += __shfl_xor(acc.y, off, 64);
        acc.z += __shfl_xor(acc.z, off, 64);
        acc.w += __shfl_xor(acc.w, off, 64);
    }
    // self-loop + bias (all lanes; lanes sharing q are identical)
    float4 sv = h4[(size_t)node * 4 + q];
    float4 bv = ((const float4*)b2)[q];
    float d2 = di * di;
    float4 v;
    v.x = fmaf(di, acc.x, fmaf(d2, sv.x, bv.x));
    v.y = fmaf(di, acc.y, fmaf(d2, sv.y, bv.y));
    v.z = fmaf(di, acc.z, fmaf(d2, sv.z, bv.z));
    v.w = fmaf(di, acc.w, fmaf(d2, sv.w, bv.w));
    // log-softmax across 16 features = 4 quads x 4 lanes (bits 0..1)
    float mr = fmaxf(fmaxf(v.x, v.y), fmaxf(v.z, v.w));
    mr = fmaxf(mr, __shfl_xor(mr, 1, 64));
    mr = fmaxf(mr, __shfl_xor(mr, 2, 64));
    float s = expf(v.x - mr) + expf(v.y - mr) + expf(v.z - mr) + expf(v.w - mr);
    s += __shfl_xor(s, 1, 64);
    s += __shfl_xor(s, 2, 64);
    float l = mr + logf(s);
    if (g == 0) {
        float4 o;
        o.x = v.x - l; o.y = v.y - l; o.z = v.z - l; o.w = v.w - l;
        ((float4*)out)[(size_t)node * 4 + q] = o;
    }
}

extern "C" void kernel_launch(void* const* d_in, const int* in_sizes, int n_in,
                              void* d_out, int out_size, void* d_ws, size_t ws_size,
                              hipStream_t stream) {
    const float* x  = (const float*)d_in[0];
    const int*   ei = (const int*)d_in[1];
    const float* W1 = (const float*)d_in[2];
    const float* b1 = (const float*)d_in[3];
    const float* W2 = (const float*)d_in[4];
    const float* b2 = (const float*)d_in[5];
    float* out = (float*)d_out;

    const int n = in_sizes[0] / F1;   // 50000
    const int e = in_sizes[1] / 2;    // 800000
    const int* src = ei;
    const int* dst = ei + e;

    const int na = (n + 63) & ~63;
    const int nb = (n + 255) / 256;

    // ws layout (4B units): dinv[na] | cnt/cursor[na] | rowstart[na+64] | bsum[256] | csr[e] | h[n*64] | agg1[n*64]
    float* dinv   = (float*)d_ws;
    int* cnt      = (int*)(dinv + na);
    int* rowstart = cnt + na;
    int* bsum     = rowstart + na + 64;
    int* csr      = bsum + 256;
    float* h      = (float*)(csr + ((e + 63) & ~63));
    float* agg1   = h + (size_t)n * F1;

    const int B = 256;
    // ---- CSR build + dinv ----
    hipMemsetAsync(cnt, 0, (size_t)n * 4, stream);
    k_count<<<(e / 4 + B - 1) / B, B, 0, stream>>>(dst, cnt, e / 4);
    k_scan1<<<nb, B, 0, stream>>>(cnt, rowstart, bsum, dinv, n);
    k_scan2<<<1, B, 0, stream>>>(bsum, nb);
    k_scan3<<<nb, B, 0, stream>>>(rowstart, cnt /*cursor*/, bsum, n, e);
    k_fill<<<(e / 4 + B - 1) / B, B, 0, stream>>>(src, dst, cnt /*cursor*/, csr, e / 4);

    // ---- layer 1 ----
    k_mgemm1<<<(n + 63) / 64, B, 0, stream>>>(x, W1, h, n);
    k_agg64<<<(n + 3) / 4, B, 0, stream>>>(rowstart, csr, dinv, h, agg1, n);

    // ---- layer 2 ----
    float* h2 = h;  // reuse
    k_mgemm2<<<(n + 63) / 64, B, 0, stream>>>(agg1, b1, W2, h2, n);
    k_agg16<<<(n + 3) / 4, B, 0, stream>>>(rowstart, csr, dinv, h2, b2, out, n);
}

// Round 4
// 171.163 us; speedup vs baseline: 2.4064x; 1.3505x over previous
//
#include <hip/hip_runtime.h>

// GCN 2-layer forward. Partition-sorted CSR build (no global f32 atomics,
// no scattered-line write amplification), MFMA GEMMs (3-term bf16 split).

#define F1 64
#define F2 16
#define G 256      // chunk blocks for partition passes
#define HP 512     // padded partition stride (max partitions, n <= 65536)

typedef __attribute__((ext_vector_type(8))) short bf16x8;
typedef __attribute__((ext_vector_type(4))) float f32x4;

// split 8 f32 into hi/lo bf16 (truncation split: h exact-high, |lo err| ~2^-17 rel)
__device__ inline void cvt8(const float* v, bf16x8& h, bf16x8& l) {
#pragma unroll
    for (int i = 0; i < 8; ++i) {
        unsigned b = __float_as_uint(v[i]);
        h[i] = (short)(b >> 16);
        float hif = __uint_as_float(b & 0xFFFF0000u);
        float lof = v[i] - hif;
        l[i] = (short)(__float_as_uint(lof) >> 16);
    }
}

// ---------------- CSR build: partition counting sort ----------------

// P1: per-chunk histogram over partitions (partition = dst >> 7)
__global__ __launch_bounds__(256) void k_hist(const int* __restrict__ dst,
                                              int* __restrict__ hist,
                                              int* __restrict__ ptotal,
                                              int e, int npart) {
    __shared__ int hl[HP];
    int tid = threadIdx.x, g = blockIdx.x;
    for (int i = tid; i < HP; i += 256) hl[i] = 0;
    __syncthreads();
    int chunk = (e + G - 1) / G;
    int beg = g * chunk, end = min(e, beg + chunk);
    for (int i = beg + tid; i < end; i += 256)
        atomicAdd(&hl[dst[i] >> 7], 1);
    __syncthreads();
    for (int p = tid; p < npart; p += 256) {
        int v = hl[p];
        hist[g * HP + p] = v;
        if (v) atomicAdd(&ptotal[p], v);
    }
}

// P2b: exclusive scan of partition totals -> part_base (npart <= 512)
__global__ __launch_bounds__(512) void k_pscan(const int* __restrict__ ptotal,
                                               int* __restrict__ part_base,
                                               int* __restrict__ rowstart,
                                               int npart, int n, int e) {
    __shared__ int s[512];
    int tid = threadIdx.x;
    int v = (tid < npart) ? ptotal[tid] : 0;
    s[tid] = v;
    __syncthreads();
    for (int off = 1; off < 512; off <<= 1) {
        int t = (tid >= off) ? s[tid - off] : 0;
        __syncthreads();
        s[tid] += t;
        __syncthreads();
    }
    if (tid < npart) part_base[tid] = s[tid] - v;
    if (tid == 0) { part_base[npart] = e; rowstart[n] = e; }
}

// P2c: per-partition scan over chunks -> per-(chunk,partition) cursors
__global__ __launch_bounds__(256) void k_cscan(const int* __restrict__ hist,
                                               const int* __restrict__ part_base,
                                               int* __restrict__ pgoff, int npart) {
    __shared__ int s[G];
    int p = blockIdx.x, g = threadIdx.x;
    int v = hist[g * HP + p];
    s[g] = v;
    __syncthreads();
    for (int off = 1; off < G; off <<= 1) {
        int t = (g >= off) ? s[g - off] : 0;
        __syncthreads();
        s[g] += t;
        __syncthreads();
    }
    pgoff[g * HP + p] = part_base[p] + s[g] - v;
}

// P3: scatter edges into partition-grouped packed pairs (block-private cursors)
__global__ __launch_bounds__(256) void k_part(const int* __restrict__ src,
                                              const int* __restrict__ dst,
                                              const int* __restrict__ pgoff,
                                              unsigned* __restrict__ pairs,
                                              int e, int npart) {
    __shared__ int cur[HP];
    int tid = threadIdx.x, g = blockIdx.x;
    for (int i = tid; i < npart; i += 256) cur[i] = pgoff[g * HP + i];
    __syncthreads();
    int chunk = (e + G - 1) / G;
    int beg = g * chunk, end = min(e, beg + chunk);
    for (int i = beg + tid; i < end; i += 256) {
        int d = dst[i], sv = src[i];
        int pos = atomicAdd(&cur[d >> 7], 1);
        pairs[pos] = ((unsigned)(d & 127) << 16) | (unsigned)sv;  // src < 2^16
    }
}

// P4: per-partition CSR finalize; fuses rowstart + dinv
__global__ __launch_bounds__(256) void k_csr(const unsigned* __restrict__ pairs,
                                             const int* __restrict__ part_base,
                                             int* __restrict__ rowstart,
                                             float* __restrict__ dinv,
                                             int* __restrict__ csr, int n) {
    __shared__ int cnt[128], cur[128], sc[128];
    int p = blockIdx.x, tid = threadIdx.x;
    int wbeg = part_base[p], wend = part_base[p + 1];
    if (tid < 128) cnt[tid] = 0;
    __syncthreads();
    for (int i = wbeg + tid; i < wend; i += 256)
        atomicAdd(&cnt[pairs[i] >> 16], 1);
    __syncthreads();
    if (tid < 128) sc[tid] = cnt[tid];
    __syncthreads();
    for (int off = 1; off < 128; off <<= 1) {
        int t = (tid >= off && tid < 128) ? sc[tid - off] : 0;
        __syncthreads();
        if (tid < 128) sc[tid] += t;
        __syncthreads();
    }
    if (tid < 128) {
        int v = cnt[tid];
        int rs = wbeg + sc[tid] - v;  // exclusive
        cur[tid] = rs;
        int node = (p << 7) + tid;
        if (node < n) {
            rowstart[node] = rs;
            dinv[node] = rsqrtf((float)v + 1.0f);  // +1 self loop
        }
    }
    __syncthreads();
    for (int i = wbeg + tid; i < wend; i += 256) {
        unsigned u = pairs[i];
        int pos = atomicAdd(&cur[u >> 16], 1);
        csr[pos] = (int)(u & 0xFFFFu);
    }
}

// ---------------- GEMMs (MFMA, 3-term bf16 split) ----------------

__global__ __launch_bounds__(256) void k_mgemm1(const float* __restrict__ x,
                                                const float* __restrict__ W1,
                                                float* __restrict__ h, int n) {
    __shared__ float ws[64 * 65];
    int tid = threadIdx.x;
    for (int i = tid; i < 64 * 64; i += 256) {
        int k = i >> 6, c = i & 63;
        ws[k * 65 + c] = W1[i];
    }
    __syncthreads();
    int lane = tid & 63, wv = tid >> 6;
    int rt = blockIdx.x * 64 + wv * 16;
    int r = lane & 15, g = lane >> 4;
    int row = rt + r;
    int rowc = row < n ? row : n - 1;
    const float* xp = x + (size_t)rowc * F1 + g * 8;
    bf16x8 ah[2], al[2];
#pragma unroll
    for (int kb = 0; kb < 2; ++kb) {
        float v[8];
        *(float4*)&v[0] = *(const float4*)(xp + kb * 32);
        *(float4*)&v[4] = *(const float4*)(xp + kb * 32 + 4);
        cvt8(v, ah[kb], al[kb]);
    }
#pragma unroll
    for (int ct = 0; ct < 4; ++ct) {
        bf16x8 bh[2], bl[2];
#pragma unroll
        for (int kb = 0; kb < 2; ++kb) {
            float v[8];
#pragma unroll
            for (int i = 0; i < 8; ++i)
                v[i] = ws[(kb * 32 + g * 8 + i) * 65 + ct * 16 + r];
            cvt8(v, bh[kb], bl[kb]);
        }
        f32x4 acc = {0.f, 0.f, 0.f, 0.f};
#pragma unroll
        for (int kb = 0; kb < 2; ++kb) {
            acc = __builtin_amdgcn_mfma_f32_16x16x32_bf16(ah[kb], bh[kb], acc, 0, 0, 0);
            acc = __builtin_amdgcn_mfma_f32_16x16x32_bf16(al[kb], bh[kb], acc, 0, 0, 0);
            acc = __builtin_amdgcn_mfma_f32_16x16x32_bf16(ah[kb], bl[kb], acc, 0, 0, 0);
        }
#pragma unroll
        for (int j = 0; j < 4; ++j) {
            int orow = rt + g * 4 + j;
            if (orow < n) h[(size_t)orow * F1 + ct * 16 + r] = acc[j];
        }
    }
}

__global__ __launch_bounds__(256) void k_mgemm2(const float* __restrict__ agg1,
                                                const float* __restrict__ b1,
                                                const float* __restrict__ W2,
                                                float* __restrict__ h2, int n) {
    __shared__ float ws[64 * 17];
    int tid = threadIdx.x;
    for (int i = tid; i < 64 * 16; i += 256) {
        int k = i >> 4, c = i & 15;
        ws[k * 17 + c] = W2[i];
    }
    __syncthreads();
    int lane = tid & 63, wv = tid >> 6;
    int rt = blockIdx.x * 64 + wv * 16;
    int r = lane & 15, g = lane >> 4;
    int row = rt + r;
    int rowc = row < n ? row : n - 1;
    const float* ap = agg1 + (size_t)rowc * F1 + g * 8;
    const float* bp = b1 + g * 8;
    bf16x8 ah[2], al[2];
#pragma unroll
    for (int kb = 0; kb < 2; ++kb) {
        float v[8], b[8];
        *(float4*)&v[0] = *(const float4*)(ap + kb * 32);
        *(float4*)&v[4] = *(const float4*)(ap + kb * 32 + 4);
        *(float4*)&b[0] = *(const float4*)(bp + kb * 32);
        *(float4*)&b[4] = *(const float4*)(bp + kb * 32 + 4);
#pragma unroll
        for (int i = 0; i < 8; ++i) v[i] = fmaxf(v[i] + b[i], 0.f);
        cvt8(v, ah[kb], al[kb]);
    }
    bf16x8 bh[2], bl[2];
#pragma unroll
    for (int kb = 0; kb < 2; ++kb) {
        float v[8];
#pragma unroll
        for (int i = 0; i < 8; ++i)
            v[i] = ws[(kb * 32 + g * 8 + i) * 17 + r];
        cvt8(v, bh[kb], bl[kb]);
    }
    f32x4 acc = {0.f, 0.f, 0.f, 0.f};
#pragma unroll
    for (int kb = 0; kb < 2; ++kb) {
        acc = __builtin_amdgcn_mfma_f32_16x16x32_bf16(ah[kb], bh[kb], acc, 0, 0, 0);
        acc = __builtin_amdgcn_mfma_f32_16x16x32_bf16(al[kb], bh[kb], acc, 0, 0, 0);
        acc = __builtin_amdgcn_mfma_f32_16x16x32_bf16(ah[kb], bl[kb], acc, 0, 0, 0);
    }
#pragma unroll
    for (int j = 0; j < 4; ++j) {
        int orow = rt + g * 4 + j;
        if (orow < n) h2[(size_t)orow * F2 + r] = acc[j];
    }
}

// ---------------- Aggregation (gather) ----------------

__global__ __launch_bounds__(256) void k_agg64(const int* __restrict__ rowstart,
                                               const int* __restrict__ csr,
                                               const float* __restrict__ dinv,
                                               const float* __restrict__ h,
                                               float* __restrict__ agg, int n) {
    int lane = threadIdx.x & 63, wv = threadIdx.x >> 6;
    int node = blockIdx.x * 4 + wv;
    if (node >= n) return;
    int g = lane >> 4, q = lane & 15;
    float di = dinv[node];
    const float4* h4 = (const float4*)h;
    float4 acc = {0.f, 0.f, 0.f, 0.f};
    int beg = rowstart[node], end = rowstart[node + 1];
    for (int base = beg; base < end; base += 64) {
        int k = base + lane;
        int idx = (k < end) ? csr[k] : 0;
        float dv = (k < end) ? dinv[idx] : 0.0f;
        int m = end - base;
        if (m > 64) m = 64;
        int iters = (m + 3) >> 2;
        for (int i = 0; i < iters; ++i) {
            int slot = i * 4 + g;
            int s = __shfl(idx, slot, 64);
            float w = __shfl(dv, slot, 64);
            float4 v = h4[(size_t)s * 16 + q];
            acc.x = fmaf(w, v.x, acc.x);
            acc.y = fmaf(w, v.y, acc.y);
            acc.z = fmaf(w, v.z, acc.z);
            acc.w = fmaf(w, v.w, acc.w);
        }
    }
#pragma unroll
    for (int off = 16; off <= 32; off <<= 1) {
        acc.x += __shfl_xor(acc.x, off, 64);
        acc.y += __shfl_xor(acc.y, off, 64);
        acc.z += __shfl_xor(acc.z, off, 64);
        acc.w += __shfl_xor(acc.w, off, 64);
    }
    if (g == 0) {
        float4 sv = h4[(size_t)node * 16 + q];
        float d2 = di * di;
        float4 o;
        o.x = fmaf(di, acc.x, d2 * sv.x);
        o.y = fmaf(di, acc.y, d2 * sv.y);
        o.z = fmaf(di, acc.z, d2 * sv.z);
        o.w = fmaf(di, acc.w, d2 * sv.w);
        ((float4*)agg)[(size_t)node * 16 + q] = o;
    }
}

__global__ __launch_bounds__(256) void k_agg16(const int* __restrict__ rowstart,
                                               const int* __restrict__ csr,
                                               const float* __restrict__ dinv,
                                               const float* __restrict__ h2,
                                               const float* __restrict__ b2,
                                               float* __restrict__ out, int n) {
    int lane = threadIdx.x & 63, wv = threadIdx.x >> 6;
    int node = blockIdx.x * 4 + wv;
    if (node >= n) return;
    int g = lane >> 2, q = lane & 3;
    float di = dinv[node];
    const float4* h4 = (const float4*)h2;
    float4 acc = {0.f, 0.f, 0.f, 0.f};
    int beg = rowstart[node], end = rowstart[node + 1];
    for (int base = beg; base < end; base += 64) {
        int k = base + lane;
        int idx = (k < end) ? csr[k] : 0;
        float dv = (k < end) ? dinv[idx] : 0.0f;
        int m = end - base;
        if (m > 64) m = 64;
        int iters = (m + 15) >> 4;
        for (int i = 0; i < iters; ++i) {
            int slot = i * 16 + g;
            int s = __shfl(idx, slot, 64);
            float w = __shfl(dv, slot, 64);
            float4 v = h4[(size_t)s * 4 + q];
            acc.x = fmaf(w, v.x, acc.x);
            acc.y = fmaf(w, v.y, acc.y);
            acc.z = fmaf(w, v.z, acc.z);
            acc.w = fmaf(w, v.w, acc.w);
        }
    }
#pragma unroll
    for (int off = 4; off <= 32; off <<= 1) {
        acc.x += __shfl_xor(acc.x, off, 64);
        acc.y += __shfl_xor(acc.y, off, 64);
        acc.z += __shfl_xor(acc.z, off, 64);
        acc.w += __shfl_xor(acc.w, off, 64);
    }
    float4 sv = h4[(size_t)node * 4 + q];
    float4 bv = ((const float4*)b2)[q];
    float d2 = di * di;
    float4 v;
    v.x = fmaf(di, acc.x, fmaf(d2, sv.x, bv.x));
    v.y = fmaf(di, acc.y, fmaf(d2, sv.y, bv.y));
    v.z = fmaf(di, acc.z, fmaf(d2, sv.z, bv.z));
    v.w = fmaf(di, acc.w, fmaf(d2, sv.w, bv.w));
    float mr = fmaxf(fmaxf(v.x, v.y), fmaxf(v.z, v.w));
    mr = fmaxf(mr, __shfl_xor(mr, 1, 64));
    mr = fmaxf(mr, __shfl_xor(mr, 2, 64));
    float s = expf(v.x - mr) + expf(v.y - mr) + expf(v.z - mr) + expf(v.w - mr);
    s += __shfl_xor(s, 1, 64);
    s += __shfl_xor(s, 2, 64);
    float l = mr + logf(s);
    if (g == 0) {
        float4 o;
        o.x = v.x - l; o.y = v.y - l; o.z = v.z - l; o.w = v.w - l;
        ((float4*)out)[(size_t)node * 4 + q] = o;
    }
}

extern "C" void kernel_launch(void* const* d_in, const int* in_sizes, int n_in,
                              void* d_out, int out_size, void* d_ws, size_t ws_size,
                              hipStream_t stream) {
    const float* x  = (const float*)d_in[0];
    const int*   ei = (const int*)d_in[1];
    const float* W1 = (const float*)d_in[2];
    const float* b1 = (const float*)d_in[3];
    const float* W2 = (const float*)d_in[4];
    const float* b2 = (const float*)d_in[5];
    float* out = (float*)d_out;

    const int n = in_sizes[0] / F1;   // 50000
    const int e = in_sizes[1] / 2;    // 800000
    const int* src = ei;
    const int* dst = ei + e;

    const int na = (n + 63) & ~63;
    const int npart = (n + 127) >> 7;          // 391 (<=512 for n<=65536)

    // ws layout (4B units):
    // dinv[na] | rowstart[na+64] | part_base[576] | ptotal[512] | csr[e] | h[n*64] | agg1[n*64]
    // scratch (hist/pgoff/pairs) aliases the h region (dead before k_mgemm1).
    float* dinv     = (float*)d_ws;
    int* rowstart   = (int*)(dinv + na);
    int* part_base  = rowstart + na + 64;
    int* ptotal     = part_base + 576;
    int* csr        = ptotal + 512;
    float* h        = (float*)(csr + ((e + 63) & ~63));
    float* agg1     = h + (size_t)n * F1;
    int* hist       = (int*)h;                 // G*HP
    int* pgoff      = hist + G * HP;           // G*HP
    unsigned* pairs = (unsigned*)(pgoff + G * HP);  // e

    // ---- CSR build (partition counting sort) ----
    hipMemsetAsync(ptotal, 0, HP * sizeof(int), stream);
    k_hist <<<G, 256, 0, stream>>>(dst, hist, ptotal, e, npart);
    k_pscan<<<1, 512, 0, stream>>>(ptotal, part_base, rowstart, npart, n, e);
    k_cscan<<<npart, 256, 0, stream>>>(hist, part_base, pgoff, npart);
    k_part <<<G, 256, 0, stream>>>(src, dst, pgoff, pairs, e, npart);
    k_csr  <<<npart, 256, 0, stream>>>(pairs, part_base, rowstart, dinv, csr, n);

    // ---- layer 1 ----
    k_mgemm1<<<(n + 63) / 64, 256, 0, stream>>>(x, W1, h, n);
    k_agg64<<<(n + 3) / 4, 256, 0, stream>>>(rowstart, csr, dinv, h, agg1, n);

    // ---- layer 2 ----
    float* h2 = h;  // reuse
    k_mgemm2<<<(n + 63) / 64, 256, 0, stream>>>(agg1, b1, W2, h2, n);
    k_agg16<<<(n + 3) / 4, 256, 0, stream>>>(rowstart, csr, dinv, h2, b2, out, n);
}

// Round 6
// 158.532 us; speedup vs baseline: 2.5981x; 1.0797x over previous
//
#include <hip/hip_runtime.h>

// GCN 2-layer forward. Partition counting-sort CSR build (4 kernels, LDS-only
// atomics), MFMA GEMMs (3-term bf16 split), bf16 feature tables for the
// gather-heavy aggregation (halves L2/L3 gather traffic).

#define F1 64
#define F2 16
#define G 256      // chunk blocks for partition passes
#define HP 256     // partition stride; partition = dst >> 8; npart <= 256 (n <= 65536)

typedef __attribute__((ext_vector_type(8))) short bf16x8;
typedef __attribute__((ext_vector_type(4))) float f32x4;
typedef __attribute__((ext_vector_type(4))) unsigned short u16x4;

// f32 -> bf16 round-to-nearest-even
__device__ inline unsigned short f2bf(float f) {
    unsigned u = __float_as_uint(f);
    return (unsigned short)((u + 0x7FFFu + ((u >> 16) & 1u)) >> 16);
}
__device__ inline float bf2f(unsigned short s) {
    return __uint_as_float(((unsigned)s) << 16);
}

// split 8 f32 into hi/lo bf16 (truncation split: hi exact-high, lo ~2^-17 rel)
__device__ inline void cvt8(const float* v, bf16x8& h, bf16x8& l) {
#pragma unroll
    for (int i = 0; i < 8; ++i) {
        unsigned b = __float_as_uint(v[i]);
        h[i] = (short)(b >> 16);
        float hif = __uint_as_float(b & 0xFFFF0000u);
        float lof = v[i] - hif;
        l[i] = (short)(__float_as_uint(lof) >> 16);
    }
}

// ---------------- CSR build ----------------

// P1: per-chunk histogram over partitions
__global__ __launch_bounds__(256) void k_hist(const int4* __restrict__ dst4,
                                              const int* __restrict__ dst,
                                              int* __restrict__ hist, int e4, int e) {
    __shared__ int hl[HP];
    int tid = threadIdx.x, g = blockIdx.x;
    hl[tid] = 0;
    __syncthreads();
    int chunk = (e4 + G - 1) / G;
    int beg = g * chunk, end = min(e4, beg + chunk);
    for (int i = beg + tid; i < end; i += 256) {
        int4 d = dst4[i];
        atomicAdd(&hl[d.x >> 8], 1);
        atomicAdd(&hl[d.y >> 8], 1);
        atomicAdd(&hl[d.z >> 8], 1);
        atomicAdd(&hl[d.w >> 8], 1);
    }
    if (g == G - 1)
        for (int i = e4 * 4 + tid; i < e; i += 256) atomicAdd(&hl[dst[i] >> 8], 1);
    __syncthreads();
    hist[g * HP + tid] = hl[tid];
}

// P2: per-partition scan over chunks -> local offsets + partition totals
__global__ __launch_bounds__(256) void k_cscan(const int* __restrict__ hist,
                                               int* __restrict__ pgoff,
                                               int* __restrict__ ptotal) {
    __shared__ int s[G];
    int p = blockIdx.x, g = threadIdx.x;
    int v = hist[g * HP + p];
    s[g] = v;
    __syncthreads();
    for (int off = 1; off < G; off <<= 1) {
        int t = (g >= off) ? s[g - off] : 0;
        __syncthreads();
        s[g] += t;
        __syncthreads();
    }
    pgoff[g * HP + p] = s[g] - v;  // chunk-local exclusive
    if (g == G - 1) ptotal[p] = s[g];
}

// P3: scatter edges into partition-grouped packed pairs (block-private cursors)
__global__ __launch_bounds__(256) void k_part(const int4* __restrict__ src4,
                                              const int4* __restrict__ dst4,
                                              const int* __restrict__ src,
                                              const int* __restrict__ dst,
                                              const int* __restrict__ pgoff,
                                              const int* __restrict__ ptotal,
                                              unsigned* __restrict__ pairs,
                                              int e4, int e, int npart) {
    __shared__ int s[HP];
    __shared__ int cur[HP];
    int tid = threadIdx.x, g = blockIdx.x;
    int v = (tid < npart) ? ptotal[tid] : 0;
    s[tid] = v;
    __syncthreads();
    for (int off = 1; off < HP; off <<= 1) {
        int t = (tid >= off) ? s[tid - off] : 0;
        __syncthreads();
        s[tid] += t;
        __syncthreads();
    }
    cur[tid] = (s[tid] - v) + pgoff[g * HP + tid];  // part_base + chunk offset
    __syncthreads();
    int chunk = (e4 + G - 1) / G;
    int beg = g * chunk, end = min(e4, beg + chunk);
    for (int i = beg + tid; i < end; i += 256) {
        int4 s4 = src4[i];
        int4 d4 = dst4[i];
        int pos;
        pos = atomicAdd(&cur[d4.x >> 8], 1); pairs[pos] = ((unsigned)(d4.x & 255) << 16) | (unsigned)s4.x;
        pos = atomicAdd(&cur[d4.y >> 8], 1); pairs[pos] = ((unsigned)(d4.y & 255) << 16) | (unsigned)s4.y;
        pos = atomicAdd(&cur[d4.z >> 8], 1); pairs[pos] = ((unsigned)(d4.z & 255) << 16) | (unsigned)s4.z;
        pos = atomicAdd(&cur[d4.w >> 8], 1); pairs[pos] = ((unsigned)(d4.w & 255) << 16) | (unsigned)s4.w;
    }
    if (g == G - 1)
        for (int i = e4 * 4 + tid; i < e; i += 256) {
            int d = dst[i];
            int pos = atomicAdd(&cur[d >> 8], 1);
            pairs[pos] = ((unsigned)(d & 255) << 16) | (unsigned)src[i];
        }
}

// P4: per-partition bucket sort -> csr; fuses rowstart + dinv
__global__ __launch_bounds__(256) void k_csr(const unsigned* __restrict__ pairs,
                                             const int* __restrict__ ptotal,
                                             int* __restrict__ rowstart,
                                             float* __restrict__ dinv,
                                             int* __restrict__ csr,
                                             int n, int e, int npart) {
    __shared__ int s[HP];
    __shared__ int cnt[256], cur[256];
    __shared__ int wbs, wes;
    int p = blockIdx.x, tid = threadIdx.x;
    int v = (tid < npart) ? ptotal[tid] : 0;
    s[tid] = v;
    __syncthreads();
    for (int off = 1; off < HP; off <<= 1) {
        int t = (tid >= off) ? s[tid - off] : 0;
        __syncthreads();
        s[tid] += t;
        __syncthreads();
    }
    if (tid == p) { wbs = s[tid] - v; wes = s[tid]; }
    cnt[tid] = 0;
    __syncthreads();
    int wbeg = wbs, wend = wes;
    for (int i = wbeg + tid; i < wend; i += 256)
        atomicAdd(&cnt[pairs[i] >> 16], 1);
    __syncthreads();
    int c = cnt[tid];
    s[tid] = c;
    __syncthreads();
    for (int off = 1; off < 256; off <<= 1) {
        int t = (tid >= off) ? s[tid - off] : 0;
        __syncthreads();
        s[tid] += t;
        __syncthreads();
    }
    int rs = wbeg + s[tid] - c;  // exclusive within window
    cur[tid] = rs;
    int node = (p << 8) + tid;
    if (node < n) {
        rowstart[node] = rs;
        dinv[node] = rsqrtf((float)c + 1.0f);  // +1 self loop
    }
    if (p == 0 && tid == 0) rowstart[n] = e;
    __syncthreads();
    for (int i = wbeg + tid; i < wend; i += 256) {
        unsigned u = pairs[i];
        int pos = atomicAdd(&cur[u >> 16], 1);
        csr[pos] = (int)(u & 0xFFFFu);
    }
}

// ---------------- GEMMs (MFMA, 3-term bf16 split) ----------------

// h_bf = bf16(x @ W1)
__global__ __launch_bounds__(256) void k_mgemm1(const float* __restrict__ x,
                                                const float* __restrict__ W1,
                                                unsigned short* __restrict__ h_bf, int n) {
    __shared__ float ws[64 * 65];
    int tid = threadIdx.x;
    for (int i = tid; i < 64 * 64; i += 256) {
        int k = i >> 6, c = i & 63;
        ws[k * 65 + c] = W1[i];
    }
    __syncthreads();
    int lane = tid & 63, wv = tid >> 6;
    int rt = blockIdx.x * 64 + wv * 16;
    int r = lane & 15, g = lane >> 4;
    int row = rt + r;
    int rowc = row < n ? row : n - 1;
    const float* xp = x + (size_t)rowc * F1 + g * 8;
    bf16x8 ah[2], al[2];
#pragma unroll
    for (int kb = 0; kb < 2; ++kb) {
        float v[8];
        *(float4*)&v[0] = *(const float4*)(xp + kb * 32);
        *(float4*)&v[4] = *(const float4*)(xp + kb * 32 + 4);
        cvt8(v, ah[kb], al[kb]);
    }
#pragma unroll
    for (int ct = 0; ct < 4; ++ct) {
        bf16x8 bh[2], bl[2];
#pragma unroll
        for (int kb = 0; kb < 2; ++kb) {
            float v[8];
#pragma unroll
            for (int i = 0; i < 8; ++i)
                v[i] = ws[(kb * 32 + g * 8 + i) * 65 + ct * 16 + r];
            cvt8(v, bh[kb], bl[kb]);
        }
        f32x4 acc = {0.f, 0.f, 0.f, 0.f};
#pragma unroll
        for (int kb = 0; kb < 2; ++kb) {
            acc = __builtin_amdgcn_mfma_f32_16x16x32_bf16(ah[kb], bh[kb], acc, 0, 0, 0);
            acc = __builtin_amdgcn_mfma_f32_16x16x32_bf16(al[kb], bh[kb], acc, 0, 0, 0);
            acc = __builtin_amdgcn_mfma_f32_16x16x32_bf16(ah[kb], bl[kb], acc, 0, 0, 0);
        }
#pragma unroll
        for (int j = 0; j < 4; ++j) {
            int orow = rt + g * 4 + j;
            if (orow < n) h_bf[(size_t)orow * F1 + ct * 16 + r] = f2bf(acc[j]);
        }
    }
}

// h2_bf = bf16( relu(agg1 + b1) @ W2 )
__global__ __launch_bounds__(256) void k_mgemm2(const float* __restrict__ agg1,
                                                const float* __restrict__ b1,
                                                const float* __restrict__ W2,
                                                unsigned short* __restrict__ h2_bf, int n) {
    __shared__ float ws[64 * 17];
    int tid = threadIdx.x;
    for (int i = tid; i < 64 * 16; i += 256) {
        int k = i >> 4, c = i & 15;
        ws[k * 17 + c] = W2[i];
    }
    __syncthreads();
    int lane = tid & 63, wv = tid >> 6;
    int rt = blockIdx.x * 64 + wv * 16;
    int r = lane & 15, g = lane >> 4;
    int row = rt + r;
    int rowc = row < n ? row : n - 1;
    const float* ap = agg1 + (size_t)rowc * F1 + g * 8;
    const float* bp = b1 + g * 8;
    bf16x8 ah[2], al[2];
#pragma unroll
    for (int kb = 0; kb < 2; ++kb) {
        float v[8], b[8];
        *(float4*)&v[0] = *(const float4*)(ap + kb * 32);
        *(float4*)&v[4] = *(const float4*)(ap + kb * 32 + 4);
        *(float4*)&b[0] = *(const float4*)(bp + kb * 32);
        *(float4*)&b[4] = *(const float4*)(bp + kb * 32 + 4);
#pragma unroll
        for (int i = 0; i < 8; ++i) v[i] = fmaxf(v[i] + b[i], 0.f);
        cvt8(v, ah[kb], al[kb]);
    }
    bf16x8 bh[2], bl[2];
#pragma unroll
    for (int kb = 0; kb < 2; ++kb) {
        float v[8];
#pragma unroll
        for (int i = 0; i < 8; ++i)
            v[i] = ws[(kb * 32 + g * 8 + i) * 17 + r];
        cvt8(v, bh[kb], bl[kb]);
    }
    f32x4 acc = {0.f, 0.f, 0.f, 0.f};
#pragma unroll
    for (int kb = 0; kb < 2; ++kb) {
        acc = __builtin_amdgcn_mfma_f32_16x16x32_bf16(ah[kb], bh[kb], acc, 0, 0, 0);
        acc = __builtin_amdgcn_mfma_f32_16x16x32_bf16(al[kb], bh[kb], acc, 0, 0, 0);
        acc = __builtin_amdgcn_mfma_f32_16x16x32_bf16(ah[kb], bl[kb], acc, 0, 0, 0);
    }
#pragma unroll
    for (int j = 0; j < 4; ++j) {
        int orow = rt + g * 4 + j;
        if (orow < n) h2_bf[(size_t)orow * F2 + r] = f2bf(acc[j]);
    }
}

// ---------------- Aggregation (gather, bf16 tables, f32 accumulate) ----------------

__global__ __launch_bounds__(256) void k_agg64(const int* __restrict__ rowstart,
                                               const int* __restrict__ csr,
                                               const float* __restrict__ dinv,
                                               const unsigned short* __restrict__ hb,
                                               float* __restrict__ agg, int n) {
    int lane = threadIdx.x & 63, wv = threadIdx.x >> 6;
    int node = blockIdx.x * 4 + wv;
    if (node >= n) return;
    int g = lane >> 4, q = lane & 15;
    float di = dinv[node];
    float4 acc = {0.f, 0.f, 0.f, 0.f};
    int beg = rowstart[node], end = rowstart[node + 1];
    for (int base = beg; base < end; base += 64) {
        int k = base + lane;
        int idx = (k < end) ? csr[k] : 0;
        float dv = (k < end) ? dinv[idx] : 0.0f;
        int m = end - base;
        if (m > 64) m = 64;
        int iters = (m + 3) >> 2;
        for (int i = 0; i < iters; ++i) {
            int slot = i * 4 + g;
            int s = __shfl(idx, slot, 64);
            float w = __shfl(dv, slot, 64);
            u16x4 u = *(const u16x4*)(hb + (size_t)s * F1 + q * 4);
            acc.x = fmaf(w, bf2f(u.x), acc.x);
            acc.y = fmaf(w, bf2f(u.y), acc.y);
            acc.z = fmaf(w, bf2f(u.z), acc.z);
            acc.w = fmaf(w, bf2f(u.w), acc.w);
        }
    }
#pragma unroll
    for (int off = 16; off <= 32; off <<= 1) {
        acc.x += __shfl_xor(acc.x, off, 64);
        acc.y += __shfl_xor(acc.y, off, 64);
        acc.z += __shfl_xor(acc.z, off, 64);
        acc.w += __shfl_xor(acc.w, off, 64);
    }
    if (g == 0) {
        u16x4 su = *(const u16x4*)(hb + (size_t)node * F1 + q * 4);
        float d2 = di * di;
        float4 o;
        o.x = fmaf(di, acc.x, d2 * bf2f(su.x));
        o.y = fmaf(di, acc.y, d2 * bf2f(su.y));
        o.z = fmaf(di, acc.z, d2 * bf2f(su.z));
        o.w = fmaf(di, acc.w, d2 * bf2f(su.w));
        ((float4*)agg)[(size_t)node * 16 + q] = o;
    }
}

__global__ __launch_bounds__(256) void k_agg16(const int* __restrict__ rowstart,
                                               const int* __restrict__ csr,
                                               const float* __restrict__ dinv,
                                               const unsigned short* __restrict__ h2b,
                                               const float* __restrict__ b2,
                                               float* __restrict__ out, int n) {
    int lane = threadIdx.x & 63, wv = threadIdx.x >> 6;
    int node = blockIdx.x * 4 + wv;
    if (node >= n) return;
    int g = lane >> 2, q = lane & 3;
    float di = dinv[node];
    float4 acc = {0.f, 0.f, 0.f, 0.f};
    int beg = rowstart[node], end = rowstart[node + 1];
    for (int base = beg; base < end; base += 64) {
        int k = base + lane;
        int idx = (k < end) ? csr[k] : 0;
        float dv = (k < end) ? dinv[idx] : 0.0f;
        int m = end - base;
        if (m > 64) m = 64;
        int iters = (m + 15) >> 4;
        for (int i = 0; i < iters; ++i) {
            int slot = i * 16 + g;
            int s = __shfl(idx, slot, 64);
            float w = __shfl(dv, slot, 64);
            u16x4 u = *(const u16x4*)(h2b + (size_t)s * F2 + q * 4);
            acc.x = fmaf(w, bf2f(u.x), acc.x);
            acc.y = fmaf(w, bf2f(u.y), acc.y);
            acc.z = fmaf(w, bf2f(u.z), acc.z);
            acc.w = fmaf(w, bf2f(u.w), acc.w);
        }
    }
#pragma unroll
    for (int off = 4; off <= 32; off <<= 1) {
        acc.x += __shfl_xor(acc.x, off, 64);
        acc.y += __shfl_xor(acc.y, off, 64);
        acc.z += __shfl_xor(acc.z, off, 64);
        acc.w += __shfl_xor(acc.w, off, 64);
    }
    u16x4 su = *(const u16x4*)(h2b + (size_t)node * F2 + q * 4);
    float4 bv = ((const float4*)b2)[q];
    float d2 = di * di;
    float4 v;
    v.x = fmaf(di, acc.x, fmaf(d2, bf2f(su.x), bv.x));
    v.y = fmaf(di, acc.y, fmaf(d2, bf2f(su.y), bv.y));
    v.z = fmaf(di, acc.z, fmaf(d2, bf2f(su.z), bv.z));
    v.w = fmaf(di, acc.w, fmaf(d2, bf2f(su.w), bv.w));
    float mr = fmaxf(fmaxf(v.x, v.y), fmaxf(v.z, v.w));
    mr = fmaxf(mr, __shfl_xor(mr, 1, 64));
    mr = fmaxf(mr, __shfl_xor(mr, 2, 64));
    float sm = expf(v.x - mr) + expf(v.y - mr) + expf(v.z - mr) + expf(v.w - mr);
    sm += __shfl_xor(sm, 1, 64);
    sm += __shfl_xor(sm, 2, 64);
    float l = mr + logf(sm);
    if (g == 0) {
        float4 o;
        o.x = v.x - l; o.y = v.y - l; o.z = v.z - l; o.w = v.w - l;
        ((float4*)out)[(size_t)node * 4 + q] = o;
    }
}

extern "C" void kernel_launch(void* const* d_in, const int* in_sizes, int n_in,
                              void* d_out, int out_size, void* d_ws, size_t ws_size,
                              hipStream_t stream) {
    const float* x  = (const float*)d_in[0];
    const int*   ei = (const int*)d_in[1];
    const float* W1 = (const float*)d_in[2];
    const float* b1 = (const float*)d_in[3];
    const float* W2 = (const float*)d_in[4];
    const float* b2 = (const float*)d_in[5];
    float* out = (float*)d_out;

    const int n = in_sizes[0] / F1;   // 50000
    const int e = in_sizes[1] / 2;    // 800000
    const int e4 = e >> 2;
    const int* src = ei;
    const int* dst = ei + e;

    const int na = (n + 63) & ~63;
    const int npart = (n + 255) >> 8;  // 196 (<=256 for n<=65536)

    // ws layout (4B units):
    // dinv[na] | rowstart[na+64] | ptotal[256] | csr[e] | h_bf[n*64 u16] | agg1[n*64 f32]
    // CSR-build scratch (hist/pgoff/pairs ~3.7MB) aliases h_bf (dead until k_mgemm1).
    float* dinv     = (float*)d_ws;
    int* rowstart   = (int*)(dinv + na);
    int* ptotal     = rowstart + na + 64;
    int* csr        = ptotal + 256;
    unsigned short* h_bf = (unsigned short*)(csr + ((e + 63) & ~63));
    float* agg1     = (float*)(h_bf + (size_t)n * F1);
    int* hist       = (int*)h_bf;                  // G*HP
    int* pgoff      = hist + G * HP;               // G*HP
    unsigned* pairs = (unsigned*)(pgoff + G * HP); // e
    unsigned short* h2_bf = h_bf;                  // layer-2 reuse

    // ---- CSR build ----
    k_hist <<<G, 256, 0, stream>>>((const int4*)dst, dst, hist, e4, e);
    k_cscan<<<npart, 256, 0, stream>>>(hist, pgoff, ptotal);
    k_part <<<G, 256, 0, stream>>>((const int4*)src, (const int4*)dst, src, dst,
                                   pgoff, ptotal, pairs, e4, e, npart);
    k_csr  <<<npart, 256, 0, stream>>>(pairs, ptotal, rowstart, dinv, csr, n, e, npart);

    // ---- layer 1 ----
    k_mgemm1<<<(n + 63) / 64, 256, 0, stream>>>(x, W1, h_bf, n);
    k_agg64<<<(n + 3) / 4, 256, 0, stream>>>(rowstart, csr, dinv, h_bf, agg1, n);

    // ---- layer 2 ----
    k_mgemm2<<<(n + 63) / 64, 256, 0, stream>>>(agg1, b1, W2, h2_bf, n);
    k_agg16<<<(n + 3) / 4, 256, 0, stream>>>(rowstart, csr, dinv, h2_bf, b2, out, n);
}